// Round 1
// baseline (1869.870 us; speedup 1.0000x reference)
//
#include <hip/hip_runtime.h>
#include <stdint.h>

typedef unsigned short u16t;
typedef unsigned int   u32t;
typedef unsigned long long u64t;
typedef __attribute__((ext_vector_type(4))) float f32x4;
typedef __attribute__((ext_vector_type(8))) short s16x8;

#define NB 4
#define NS 2048
#define ND 1024
#define NH 16
#define NBH 64
#define NTOK 8192
#define TOPK 204

__device__ __forceinline__ u16t f2bf(float f){
  u32t u = __builtin_bit_cast(u32t, f);
  u32t r = (u + 0x7FFFu + ((u >> 16) & 1u)) >> 16;
  return (u16t)r;
}
__device__ __forceinline__ float bf2f(u16t h){
  u32t u = ((u32t)h) << 16;
  return __builtin_bit_cast(float, u);
}
// monotonic order-preserving u16 key for bf16 bits
__device__ __forceinline__ u16t mono16(u16t u){
  return (u & 0x8000u) ? (u16t)(~u) : (u16t)(u | 0x8000u);
}
__device__ __forceinline__ u16t unmono16(u16t k){
  return (k & 0x8000u) ? (u16t)(k & 0x7FFFu) : (u16t)(~k);
}
__device__ __forceinline__ f32x4 mfma16(s16x8 a, s16x8 b, f32x4 c){
  return __builtin_amdgcn_mfma_f32_16x16x32_bf16(a, b, c, 0, 0, 0);
}

#define SWZ(r) (((r) & 7) << 4)

// ---------------- split / convert kernels ----------------
__global__ __launch_bounds__(256) void split_pair_kernel(const float* __restrict__ src,
    u16t* __restrict__ hi, u16t* __restrict__ lo, int n4){
  int i = blockIdx.x * 256 + threadIdx.x;
  if (i >= n4) return;
  float4 v = ((const float4*)src)[i];
  float a0=v.x, a1=v.y, a2=v.z, a3=v.w;
  u16t h0=f2bf(a0), h1=f2bf(a1), h2=f2bf(a2), h3=f2bf(a3);
  u16t l0=f2bf(a0-bf2f(h0)), l1=f2bf(a1-bf2f(h1)), l2=f2bf(a2-bf2f(h2)), l3=f2bf(a3-bf2f(h3));
  ((u64t*)hi)[i] = (u64t)h0 | ((u64t)h1<<16) | ((u64t)h2<<32) | ((u64t)h3<<48);
  ((u64t*)lo)[i] = (u64t)l0 | ((u64t)l1<<16) | ((u64t)l2<<32) | ((u64t)l3<<48);
}

__global__ __launch_bounds__(256) void cvt_kernel(const float* __restrict__ src,
    u16t* __restrict__ dst, int n4){
  int i = blockIdx.x * 256 + threadIdx.x;
  if (i >= n4) return;
  float4 v = ((const float4*)src)[i];
  u16t h0=f2bf(v.x), h1=f2bf(v.y), h2=f2bf(v.z), h3=f2bf(v.w);
  ((u64t*)dst)[i] = (u64t)h0 | ((u64t)h1<<16) | ((u64t)h2<<32) | ((u64t)h3<<48);
}

// ---------------- QKV GEMM: C[8192,3072] = (xh+xl)(Wh+Wl)^T + b, split 3-pass ----------------
__global__ __launch_bounds__(256) void qkv_gemm_kernel(
    const u16t* __restrict__ Ah, const u16t* __restrict__ Al,
    const u16t* __restrict__ Bh, const u16t* __restrict__ Bl,
    const float* __restrict__ bias,
    float* __restrict__ qout, u16t* __restrict__ khi, u16t* __restrict__ klo,
    u16t* __restrict__ vt)
{
  __shared__ u16t lds[4*4096]; // 4 planes (Ah,Al,Bh,Bl) of [128][32] bf16, swizzled
  const int tid = threadIdx.x;
  const int l = tid & 63, w = tid >> 6;
  const int wr = w >> 1, wc = w & 1;
  const int mt = blockIdx.y, nt = blockIdx.x;
  f32x4 acc[4][4] = {};
  for (int ks = 0; ks < 32; ++ks){
    __syncthreads();
    #pragma unroll
    for (int p = 0; p < 4; ++p){
      const u16t* src = (p==0) ? Ah : (p==1) ? Al : (p==2) ? Bh : Bl;
      int rb = ((p < 2) ? mt : nt) * 128;
      #pragma unroll
      for (int ii = 0; ii < 2; ++ii){
        int c = tid + ii*256;      // 512 16B-chunks per plane
        int row = c >> 2, kc = c & 3;
        s16x8 v = *(const s16x8*)(src + (size_t)(rb + row)*1024 + ks*32 + kc*8);
        *(s16x8*)((char*)lds + p*8192 + ((row*64 + kc*16) ^ SWZ(row))) = v;
      }
    }
    __syncthreads();
    s16x8 afh[4], afl[4], bfh[4], bfl[4];
    const int kb = (l >> 4) * 16;
    #pragma unroll
    for (int i = 0; i < 4; ++i){
      int row = wr*64 + i*16 + (l & 15);
      int off = (row*64 + kb) ^ SWZ(row);
      afh[i] = *(const s16x8*)((char*)lds + off);
      afl[i] = *(const s16x8*)((char*)lds + 8192 + off);
    }
    #pragma unroll
    for (int j = 0; j < 4; ++j){
      int row = wc*64 + j*16 + (l & 15);
      int off = (row*64 + kb) ^ SWZ(row);
      bfh[j] = *(const s16x8*)((char*)lds + 16384 + off);
      bfl[j] = *(const s16x8*)((char*)lds + 24576 + off);
    }
    #pragma unroll
    for (int i = 0; i < 4; ++i)
      #pragma unroll
      for (int j = 0; j < 4; ++j){
        acc[i][j] = mfma16(afh[i], bfh[j], acc[i][j]);
        acc[i][j] = mfma16(afh[i], bfl[j], acc[i][j]);
        acc[i][j] = mfma16(afl[i], bfh[j], acc[i][j]);
      }
  }
  // epilogue: scatter to q (f32), K hi/lo (bf16), V transposed (bf16)
  #pragma unroll
  for (int j = 0; j < 4; ++j){
    int col = nt*128 + wc*64 + j*16 + (l & 15);
    float bv = bias[col];
    #pragma unroll
    for (int i = 0; i < 4; ++i){
      int tok0 = mt*128 + wr*64 + i*16 + (l >> 4)*4;
      int b = tok0 >> 11;
      int s0 = tok0 & 2047;
      if (col < 1024){
        int h = col >> 6, d = col & 63;
        float* dst = qout + ((size_t)(b*NH + h)*NS + s0)*64 + d;
        #pragma unroll
        for (int r = 0; r < 4; ++r) dst[(size_t)r*64] = acc[i][j][r] + bv;
      } else if (col < 2048){
        int ch = col - 1024; int h = ch >> 6, d = ch & 63;
        size_t idx = ((size_t)(b*NH + h)*NS + s0)*64 + d;
        #pragma unroll
        for (int r = 0; r < 4; ++r){
          float v0 = acc[i][j][r] + bv;
          u16t hh = f2bf(v0);
          khi[idx + (size_t)r*64] = hh;
          klo[idx + (size_t)r*64] = f2bf(v0 - bf2f(hh));
        }
      } else {
        int ch = col - 2048; int h = ch >> 6, d = ch & 63;
        u32t p0 = (u32t)f2bf(acc[i][j][0] + bv) | ((u32t)f2bf(acc[i][j][1] + bv) << 16);
        u32t p1 = (u32t)f2bf(acc[i][j][2] + bv) | ((u32t)f2bf(acc[i][j][3] + bv) << 16);
        u64t pk = (u64t)p0 | ((u64t)p1 << 32);
        *(u64t*)(vt + ((size_t)(b*NH + h)*64 + d)*NS + s0) = pk; // 4 consecutive s packed
      }
    }
  }
}

// ---------------- out GEMM: Y[8192,1024] = A(bf16) @ Wo^T(bf16) + bo, f32 out ----------------
__global__ __launch_bounds__(256) void out_gemm_kernel(
    const u16t* __restrict__ A, const u16t* __restrict__ Bt,
    const float* __restrict__ bias, float* __restrict__ Y)
{
  __shared__ u16t lds[2*4096];
  const int tid = threadIdx.x;
  const int l = tid & 63, w = tid >> 6;
  const int wr = w >> 1, wc = w & 1;
  const int mt = blockIdx.y, nt = blockIdx.x;
  f32x4 acc[4][4] = {};
  for (int ks = 0; ks < 32; ++ks){
    __syncthreads();
    #pragma unroll
    for (int p = 0; p < 2; ++p){
      const u16t* src = p ? Bt : A;
      int rb = (p ? nt : mt) * 128;
      #pragma unroll
      for (int ii = 0; ii < 2; ++ii){
        int c = tid + ii*256;
        int row = c >> 2, kc = c & 3;
        s16x8 v = *(const s16x8*)(src + (size_t)(rb + row)*1024 + ks*32 + kc*8);
        *(s16x8*)((char*)lds + p*8192 + ((row*64 + kc*16) ^ SWZ(row))) = v;
      }
    }
    __syncthreads();
    s16x8 af[4], bf[4];
    const int kb = (l >> 4) * 16;
    #pragma unroll
    for (int i = 0; i < 4; ++i){
      int row = wr*64 + i*16 + (l & 15);
      af[i] = *(const s16x8*)((char*)lds + ((row*64 + kb) ^ SWZ(row)));
    }
    #pragma unroll
    for (int j = 0; j < 4; ++j){
      int row = wc*64 + j*16 + (l & 15);
      bf[j] = *(const s16x8*)((char*)lds + 8192 + ((row*64 + kb) ^ SWZ(row)));
    }
    #pragma unroll
    for (int i = 0; i < 4; ++i)
      #pragma unroll
      for (int j = 0; j < 4; ++j)
        acc[i][j] = mfma16(af[i], bf[j], acc[i][j]);
  }
  #pragma unroll
  for (int j = 0; j < 4; ++j){
    int col = nt*128 + wc*64 + j*16 + (l & 15);
    float bv = bias[col];
    #pragma unroll
    for (int i = 0; i < 4; ++i){
      int tok0 = mt*128 + wr*64 + i*16 + (l >> 4)*4;
      float* dst = Y + (size_t)tok0*1024 + col;
      #pragma unroll
      for (int r = 0; r < 4; ++r) dst[(size_t)r*1024] = acc[i][j][r] + bv;
    }
  }
}

// ---------------- histogram rank-select helper (wave-wide, 256 bins) ----------------
__device__ __forceinline__ void hist_select(const u32t* h, int l, int target,
                                            int& bin, int& cgt, int& hb){
  u32t h0 = h[l*4+0], h1 = h[l*4+1], h2 = h[l*4+2], h3 = h[l*4+3];
  u32t lsum = h0 + h1 + h2 + h3;
  u32t p = lsum;
  #pragma unroll
  for (int o = 1; o < 64; o <<= 1){
    u32t q = (u32t)__shfl_up((int)p, o);
    if (l >= o) p += q;
  }
  u32t total = (u32t)__shfl((int)p, 63);
  u32t gtb = total - p;                 // count in bins >= (l+1)*4
  u32t cg3 = gtb, cg2 = gtb + h3, cg1 = gtb + h3 + h2, cg0 = gtb + h3 + h2 + h1;
  int lb = -1; u32t lcg = 0, lhb = 0;
  u32t t = (u32t)target;
  if      (cg3 < t && t <= cg3 + h3){ lb = l*4+3; lcg = cg3; lhb = h3; }
  else if (cg2 < t && t <= cg2 + h2){ lb = l*4+2; lcg = cg2; lhb = h2; }
  else if (cg1 < t && t <= cg1 + h1){ lb = l*4+1; lcg = cg1; lhb = h1; }
  else if (cg0 < t && t <= cg0 + h0){ lb = l*4+0; lcg = cg0; lhb = h0; }
  u64t bm = __ballot(lb >= 0);
  int src = __ffsll((unsigned long long)bm) - 1;
  bin = __shfl(lb, src);
  cgt = __shfl((int)lcg, src);
  hb  = __shfl((int)lhb, src);
}

// ---------------- fused sparse attention: 1 WG = (bh, 32 q-rows) ----------------
__global__ __launch_bounds__(256) void attn_kernel(
    const float* __restrict__ qbuf, const u16t* __restrict__ khi,
    const u16t* __restrict__ klo, const u16t* __restrict__ vtg,
    u16t* __restrict__ aout)
{
  extern __shared__ char smem[];
  char* Sb = smem;                        // 131072: scores->weights [32][2048] bf16, swizzled
  char* KV = smem + 131072;               // 16384: K hi(0)/lo(8192) tiles; V tile reuses
  char* Qb = smem + 147456;               // 8192: Q hi(0)/lo(4096) [32][64] bf16
  u32t* hist  = (u32t*)(smem + 155648);   // [4][256]
  float* cval = (float*)(smem + 159744);  // [4][64]
  float* Zrow = (float*)(smem + 160768);  // [32]

  const int tid = threadIdx.x;
  const int l = tid & 63, w = tid >> 6;
  int lid = ((blockIdx.x & 7) << 9) | (blockIdx.x >> 3); // XCD-chunked swizzle (4096%8==0)
  const int bh = lid >> 6, qt = lid & 63;
  const size_t qbase = ((size_t)bh*NS + qt*32)*64;
  const size_t kbase = (size_t)bh*NS*64;

  // Phase 0: load + split Q
  {
    int row = tid >> 3, d0 = (tid & 7) * 8;
    const float* src = qbuf + qbase + row*64 + d0;
    float4 va = *(const float4*)src;
    float4 vb = *(const float4*)(src + 4);
    float vv[8] = {va.x,va.y,va.z,va.w,vb.x,vb.y,vb.z,vb.w};
    s16x8 ph, pl;
    #pragma unroll
    for (int e = 0; e < 8; ++e){
      u16t hh = f2bf(vv[e]);
      ph[e] = (short)hh;
      pl[e] = (short)f2bf(vv[e] - bf2f(hh));
    }
    int off = (row*128 + d0*2) ^ SWZ(row);
    *(s16x8*)(Qb + off) = ph;
    *(s16x8*)(Qb + 4096 + off) = pl;
  }
  __syncthreads();
  s16x8 qh[2][2], ql[2][2];
  #pragma unroll
  for (int rg = 0; rg < 2; ++rg)
    #pragma unroll
    for (int c = 0; c < 2; ++c){
      int row = rg*16 + (l & 15);
      int off = (row*128 + (c*32 + (l>>4)*8)*2) ^ SWZ(row);
      qh[rg][c] = *(const s16x8*)(Qb + off);
      ql[rg][c] = *(const s16x8*)(Qb + 4096 + off);
    }

  // Phase 1: QK^T (split 3-pass), scores -> Sb as bf16 (scaled by 1/8)
  for (int kt = 0; kt < 32; ++kt){
    __syncthreads();
    #pragma unroll
    for (int ii = 0; ii < 2; ++ii){
      int idx = tid + ii*256;
      int tok = idx >> 3, part = idx & 7;
      size_t g = kbase + (size_t)(kt*64 + tok)*64 + part*8;
      s16x8 vh = *(const s16x8*)(khi + g);
      s16x8 vl = *(const s16x8*)(klo + g);
      int off = (tok*128 + part*16) ^ SWZ(tok);
      *(s16x8*)(KV + off) = vh;
      *(s16x8*)(KV + 8192 + off) = vl;
    }
    __syncthreads();
    s16x8 kfh[2], kfl[2];
    #pragma unroll
    for (int c = 0; c < 2; ++c){
      int tok = w*16 + (l & 15);
      int off = (tok*128 + (c*32 + (l>>4)*8)*2) ^ SWZ(tok);
      kfh[c] = *(const s16x8*)(KV + off);
      kfl[c] = *(const s16x8*)(KV + 8192 + off);
    }
    #pragma unroll
    for (int rg = 0; rg < 2; ++rg){
      f32x4 acc = {};
      #pragma unroll
      for (int c = 0; c < 2; ++c){
        acc = mfma16(qh[rg][c], kfh[c], acc);
        acc = mfma16(qh[rg][c], kfl[c], acc);
        acc = mfma16(ql[rg][c], kfh[c], acc);
      }
      #pragma unroll
      for (int r = 0; r < 4; ++r){
        int row = rg*16 + (l>>4)*4 + r;
        int col = kt*64 + w*16 + (l & 15);
        *(u16t*)(Sb + ((row*4096 + col*2) ^ SWZ(row))) = f2bf(acc[r] * 0.125f);
      }
    }
  }
  __syncthreads();

  // Phase 2+3: per-row exact top-204 threshold + weights (wave w owns rows w*8..w*8+7)
  u32t* myhist = hist + w*256;
  float* mycval = cval + w*64;
  for (int rr = 0; rr < 8; ++rr){
    int row = w*8 + rr;
    int rswz = SWZ(row);
    u16t kx[4][8];
    u32t lmax = 0;
    #pragma unroll
    for (int i = 0; i < 4; ++i){
      int off = (row*4096 + i*1024 + l*16) ^ rswz;
      s16x8 v = *(const s16x8*)(Sb + off);
      #pragma unroll
      for (int e = 0; e < 8; ++e){
        u16t kk = mono16((u16t)v[e]);
        kx[i][e] = kk;
        lmax = lmax > (u32t)kk ? lmax : (u32t)kk;
      }
    }
    #pragma unroll
    for (int o = 32; o; o >>= 1){
      u32t ot = (u32t)__shfl_xor((int)lmax, o);
      lmax = lmax > ot ? lmax : ot;
    }
    float mx = fmaxf(bf2f(unmono16((u16t)lmax)), 0.0f); // max(sparse_scores)

    // L1 histogram (key high byte)
    #pragma unroll
    for (int z = 0; z < 4; ++z) myhist[l*4 + z] = 0;
    #pragma unroll
    for (int i = 0; i < 4; ++i)
      #pragma unroll
      for (int e = 0; e < 8; ++e)
        atomicAdd(&myhist[kx[i][e] >> 8], 1u);
    int bin1, cgt1, hb1;
    hist_select(myhist, l, TOPK, bin1, cgt1, hb1);
    int r1 = TOPK - cgt1;
    // L2 histogram (low byte, prefix-matching keys only)
    #pragma unroll
    for (int z = 0; z < 4; ++z) myhist[l*4 + z] = 0;
    #pragma unroll
    for (int i = 0; i < 4; ++i)
      #pragma unroll
      for (int e = 0; e < 8; ++e)
        if ((int)(kx[i][e] >> 8) == bin1) atomicAdd(&myhist[kx[i][e] & 255], 1u);
    int bin2, cgt2, m;
    hist_select(myhist, l, r1, bin2, cgt2, m);
    int rk = r1 - cgt2;                  // 1-based rank inside bucket
    u16t kbt = (u16t)((bin1 << 8) | bin2);

    if (rk < m){ // need exact f32 order inside the threshold bucket
      int cnt = 0;
      #pragma unroll
      for (int i = 0; i < 4; ++i)
        #pragma unroll
        for (int e = 0; e < 8; ++e){
          u64t mask = __ballot(kx[i][e] == kbt);
          while (mask && cnt < 64){
            int j = __ffsll((unsigned long long)mask) - 1;
            mask &= mask - 1;
            int tok = i*512 + j*8 + e;
            int qoff2 = (row*128 + l*2) ^ rswz;
            float qv = bf2f(*(const u16t*)(Qb + qoff2)) + bf2f(*(const u16t*)(Qb + 4096 + qoff2));
            size_t g = kbase + (size_t)tok*64 + l;
            float kv = bf2f(khi[g]) + bf2f(klo[g]);
            float pr = qv * kv;
            #pragma unroll
            for (int o = 32; o; o >>= 1) pr += __shfl_xor(pr, o);
            if (l == 0) mycval[cnt] = pr * 0.125f;
            cnt++;
          }
        }
      float x = (l < cnt) ? mycval[l] : -3e38f;
      int gt = 0, eq = 0;
      for (int jj = 0; jj < cnt; ++jj){
        float vj = mycval[jj];
        gt += (vj > x);
        eq += (vj == x);
      }
      bool ok = (l < cnt) && (gt < rk) && (rk <= gt + eq);
      u64t bm2 = __ballot(ok);
      int s2 = __ffsll((unsigned long long)bm2) - 1;
      float tval = __shfl(x, s2);        // exact rk-th largest in bucket
      int c2 = 0;
      #pragma unroll
      for (int i = 0; i < 4; ++i)
        #pragma unroll
        for (int e = 0; e < 8; ++e){
          u64t mask = __ballot(kx[i][e] == kbt);
          while (mask && c2 < 64){
            int j = __ffsll((unsigned long long)mask) - 1;
            mask &= mask - 1;
            float vv2 = mycval[c2];
            c2++;
            if (l == j && vv2 < tval) kx[i][e] = 0; // demote below-threshold bucket members
          }
        }
    }
    // weights: kept -> exp(s-mx); masked -> exp(-mx); write back bf16 in place; Z
    float em = __expf(-mx);
    float zs = 0.f;
    #pragma unroll
    for (int i = 0; i < 4; ++i){
      s16x8 wv;
      #pragma unroll
      for (int e = 0; e < 8; ++e){
        u16t kk = kx[i][e];
        float wgt;
        if (kk >= kbt){
          float sv = bf2f(unmono16(kk));
          wgt = __expf(sv - mx);
        } else wgt = em;
        zs += wgt;
        wv[e] = (short)f2bf(wgt);
      }
      int off = (row*4096 + i*1024 + l*16) ^ rswz;
      *(s16x8*)(Sb + off) = wv;
    }
    #pragma unroll
    for (int o = 32; o; o >>= 1) zs += __shfl_xor(zs, o);
    if (l == 0) Zrow[row] = zs + 1e-9f;
  }
  __syncthreads();

  // Phase 4: PV (wave w owns d-block w*16..w*16+15)
  f32x4 pacc[2] = {};
  for (int kt = 0; kt < 32; ++kt){
    #pragma unroll
    for (int ii = 0; ii < 2; ++ii){
      int idx = tid + ii*256;
      int d = idx >> 3, part = idx & 7;
      size_t g = ((size_t)bh*64 + d)*NS + kt*64 + part*8;
      s16x8 vv = *(const s16x8*)(vtg + g);
      int off = (d*128 + part*16) ^ SWZ(d);
      *(s16x8*)(KV + off) = vv;
    }
    __syncthreads();
    #pragma unroll
    for (int rg = 0; rg < 2; ++rg){
      #pragma unroll
      for (int c = 0; c < 2; ++c){
        int arow = rg*16 + (l & 15);
        s16x8 af = *(const s16x8*)(Sb + ((arow*4096 + (kt*64 + c*32 + (l>>4)*8)*2) ^ SWZ(arow)));
        int vd = w*16 + (l & 15);
        s16x8 bv = *(const s16x8*)(KV + ((vd*128 + (c*32 + (l>>4)*8)*2) ^ SWZ(vd)));
        pacc[rg] = mfma16(af, bv, pacc[rg]);
      }
    }
    __syncthreads();
  }
  // epilogue: normalize, store attn-out bf16 [B][S][H*64]
  {
    int b = bh >> 4, h = bh & 15;
    #pragma unroll
    for (int rg = 0; rg < 2; ++rg){
      #pragma unroll
      for (int r = 0; r < 4; ++r){
        int row = rg*16 + (l>>4)*4 + r;
        float val = pacc[rg][r] / Zrow[row];
        int tok = qt*32 + row;
        aout[((size_t)b*NS + tok)*1024 + h*64 + w*16 + (l & 15)] = f2bf(val);
      }
    }
  }
}

// ---------------- workspace layout ----------------
#define O_XHI  ((size_t)0)
#define O_XLO  (O_XHI + (size_t)NTOK*ND*2)
#define O_WQH  (O_XLO + (size_t)NTOK*ND*2)
#define O_WQL  (O_WQH + (size_t)3072*1024*2)
#define O_WOB  (O_WQL + (size_t)3072*1024*2)
#define O_Q    (O_WOB + (size_t)1024*1024*2)
#define O_KHI  (O_Q   + (size_t)NBH*NS*64*4)
#define O_KLO  (O_KHI + (size_t)NBH*NS*64*2)
#define O_VT   (O_KLO + (size_t)NBH*NS*64*2)
#define O_AOUT O_XHI   /* alias: x_hi dead after QKV GEMM */
#define WS_NEED (O_VT + (size_t)NBH*NS*64*2)

extern "C" void kernel_launch(void* const* d_in, const int* in_sizes, int n_in,
                              void* d_out, int out_size, void* d_ws, size_t ws_size,
                              hipStream_t stream)
{
  (void)in_sizes; (void)n_in; (void)out_size;
  const float* x    = (const float*)d_in[0];
  const float* Wqkv = (const float*)d_in[1];
  const float* bqkv = (const float*)d_in[2];
  const float* Wo   = (const float*)d_in[3];
  const float* bo   = (const float*)d_in[4];
  float* Y = (float*)d_out;
  char* ws = (char*)d_ws;
  if (ws_size < WS_NEED) return;

  u16t* xhi  = (u16t*)(ws + O_XHI);
  u16t* xlo  = (u16t*)(ws + O_XLO);
  u16t* wqh  = (u16t*)(ws + O_WQH);
  u16t* wql  = (u16t*)(ws + O_WQL);
  u16t* wob  = (u16t*)(ws + O_WOB);
  float* qbuf = (float*)(ws + O_Q);
  u16t* khi  = (u16t*)(ws + O_KHI);
  u16t* klo  = (u16t*)(ws + O_KLO);
  u16t* vt   = (u16t*)(ws + O_VT);
  u16t* aout = (u16t*)(ws + O_AOUT);

  hipFuncSetAttribute((const void*)attn_kernel,
                      hipFuncAttributeMaxDynamicSharedMemorySize, 161024);

  split_pair_kernel<<<(NTOK*ND/4)/256, 256, 0, stream>>>(x, xhi, xlo, NTOK*ND/4);
  split_pair_kernel<<<(3072*1024/4)/256, 256, 0, stream>>>(Wqkv, wqh, wql, 3072*1024/4);
  cvt_kernel<<<(1024*1024/4)/256, 256, 0, stream>>>(Wo, wob, 1024*1024/4);
  qkv_gemm_kernel<<<dim3(24, 64), 256, 0, stream>>>(xhi, xlo, wqh, wql, bqkv,
                                                    qbuf, khi, klo, vt);
  attn_kernel<<<4096, 256, 161024, stream>>>(qbuf, khi, klo, vt, aout);
  out_gemm_kernel<<<dim3(8, 64), 256, 0, stream>>>(aout, wob, bo, Y);
}

// Round 2
// 1701.021 us; speedup vs baseline: 1.0993x; 1.0993x over previous
//
#include <hip/hip_runtime.h>
#include <stdint.h>

typedef unsigned short u16t;
typedef unsigned int   u32t;
typedef unsigned long long u64t;
typedef __attribute__((ext_vector_type(4))) float f32x4;
typedef __attribute__((ext_vector_type(8))) short s16x8;

#define NB 4
#define NS 2048
#define ND 1024
#define NH 16
#define NBH 64
#define NTOK 8192
#define TOPK 204

__device__ __forceinline__ u16t f2bf(float f){
  u32t u = __builtin_bit_cast(u32t, f);
  u32t r = (u + 0x7FFFu + ((u >> 16) & 1u)) >> 16;
  return (u16t)r;
}
__device__ __forceinline__ float bf2f(u16t h){
  u32t u = ((u32t)h) << 16;
  return __builtin_bit_cast(float, u);
}
// monotonic order-preserving u16 key for bf16 bits
__device__ __forceinline__ u16t mono16(u16t u){
  return (u & 0x8000u) ? (u16t)(~u) : (u16t)(u | 0x8000u);
}
__device__ __forceinline__ u16t unmono16(u16t k){
  return (k & 0x8000u) ? (u16t)(k & 0x7FFFu) : (u16t)(~k);
}
__device__ __forceinline__ f32x4 mfma16(s16x8 a, s16x8 b, f32x4 c){
  return __builtin_amdgcn_mfma_f32_16x16x32_bf16(a, b, c, 0, 0, 0);
}
__device__ __forceinline__ u64t sxor64(u64t v, int o){
  u32t lo = (u32t)v, hi = (u32t)(v >> 32);
  lo = (u32t)__shfl_xor((int)lo, o);
  hi = (u32t)__shfl_xor((int)hi, o);
  return (u64t)lo | ((u64t)hi << 32);
}

#define SWZ(r) (((r) & 7) << 4)

// ---------------- split / convert kernels ----------------
__global__ __launch_bounds__(256) void split_pair_kernel(const float* __restrict__ src,
    u16t* __restrict__ hi, u16t* __restrict__ lo, int n4){
  int i = blockIdx.x * 256 + threadIdx.x;
  if (i >= n4) return;
  float4 v = ((const float4*)src)[i];
  float a0=v.x, a1=v.y, a2=v.z, a3=v.w;
  u16t h0=f2bf(a0), h1=f2bf(a1), h2=f2bf(a2), h3=f2bf(a3);
  u16t l0=f2bf(a0-bf2f(h0)), l1=f2bf(a1-bf2f(h1)), l2=f2bf(a2-bf2f(h2)), l3=f2bf(a3-bf2f(h3));
  ((u64t*)hi)[i] = (u64t)h0 | ((u64t)h1<<16) | ((u64t)h2<<32) | ((u64t)h3<<48);
  ((u64t*)lo)[i] = (u64t)l0 | ((u64t)l1<<16) | ((u64t)l2<<32) | ((u64t)l3<<48);
}

__global__ __launch_bounds__(256) void cvt_kernel(const float* __restrict__ src,
    u16t* __restrict__ dst, int n4){
  int i = blockIdx.x * 256 + threadIdx.x;
  if (i >= n4) return;
  float4 v = ((const float4*)src)[i];
  u16t h0=f2bf(v.x), h1=f2bf(v.y), h2=f2bf(v.z), h3=f2bf(v.w);
  ((u64t*)dst)[i] = (u64t)h0 | ((u64t)h1<<16) | ((u64t)h2<<32) | ((u64t)h3<<48);
}

// ---------------- QKV GEMM: C[8192,3072] = (xh+xl)(Wh+Wl)^T + b, split 3-pass ----------------
__global__ __launch_bounds__(256) void qkv_gemm_kernel(
    const u16t* __restrict__ Ah, const u16t* __restrict__ Al,
    const u16t* __restrict__ Bh, const u16t* __restrict__ Bl,
    const float* __restrict__ bias,
    float* __restrict__ qout, u16t* __restrict__ khi, u16t* __restrict__ klo,
    u16t* __restrict__ vt)
{
  __shared__ u16t lds[4*4096]; // 4 planes (Ah,Al,Bh,Bl) of [128][32] bf16, swizzled
  const int tid = threadIdx.x;
  const int l = tid & 63, w = tid >> 6;
  const int wr = w >> 1, wc = w & 1;
  const int mt = blockIdx.y, nt = blockIdx.x;
  f32x4 acc[4][4] = {};
  for (int ks = 0; ks < 32; ++ks){
    __syncthreads();
    #pragma unroll
    for (int p = 0; p < 4; ++p){
      const u16t* src = (p==0) ? Ah : (p==1) ? Al : (p==2) ? Bh : Bl;
      int rb = ((p < 2) ? mt : nt) * 128;
      #pragma unroll
      for (int ii = 0; ii < 2; ++ii){
        int c = tid + ii*256;      // 512 16B-chunks per plane
        int row = c >> 2, kc = c & 3;
        s16x8 v = *(const s16x8*)(src + (size_t)(rb + row)*1024 + ks*32 + kc*8);
        *(s16x8*)((char*)lds + p*8192 + ((row*64 + kc*16) ^ SWZ(row))) = v;
      }
    }
    __syncthreads();
    s16x8 afh[4], afl[4], bfh[4], bfl[4];
    const int kb = (l >> 4) * 16;
    #pragma unroll
    for (int i = 0; i < 4; ++i){
      int row = wr*64 + i*16 + (l & 15);
      int off = (row*64 + kb) ^ SWZ(row);
      afh[i] = *(const s16x8*)((char*)lds + off);
      afl[i] = *(const s16x8*)((char*)lds + 8192 + off);
    }
    #pragma unroll
    for (int j = 0; j < 4; ++j){
      int row = wc*64 + j*16 + (l & 15);
      int off = (row*64 + kb) ^ SWZ(row);
      bfh[j] = *(const s16x8*)((char*)lds + 16384 + off);
      bfl[j] = *(const s16x8*)((char*)lds + 24576 + off);
    }
    #pragma unroll
    for (int i = 0; i < 4; ++i)
      #pragma unroll
      for (int j = 0; j < 4; ++j){
        acc[i][j] = mfma16(afh[i], bfh[j], acc[i][j]);
        acc[i][j] = mfma16(afh[i], bfl[j], acc[i][j]);
        acc[i][j] = mfma16(afl[i], bfh[j], acc[i][j]);
      }
  }
  // epilogue: scatter to q (f32), K hi/lo (bf16), V transposed (bf16)
  #pragma unroll
  for (int j = 0; j < 4; ++j){
    int col = nt*128 + wc*64 + j*16 + (l & 15);
    float bv = bias[col];
    #pragma unroll
    for (int i = 0; i < 4; ++i){
      int tok0 = mt*128 + wr*64 + i*16 + (l >> 4)*4;
      int b = tok0 >> 11;
      int s0 = tok0 & 2047;
      if (col < 1024){
        int h = col >> 6, d = col & 63;
        float* dst = qout + ((size_t)(b*NH + h)*NS + s0)*64 + d;
        #pragma unroll
        for (int r = 0; r < 4; ++r) dst[(size_t)r*64] = acc[i][j][r] + bv;
      } else if (col < 2048){
        int ch = col - 1024; int h = ch >> 6, d = ch & 63;
        size_t idx = ((size_t)(b*NH + h)*NS + s0)*64 + d;
        #pragma unroll
        for (int r = 0; r < 4; ++r){
          float v0 = acc[i][j][r] + bv;
          u16t hh = f2bf(v0);
          khi[idx + (size_t)r*64] = hh;
          klo[idx + (size_t)r*64] = f2bf(v0 - bf2f(hh));
        }
      } else {
        int ch = col - 2048; int h = ch >> 6, d = ch & 63;
        u32t p0 = (u32t)f2bf(acc[i][j][0] + bv) | ((u32t)f2bf(acc[i][j][1] + bv) << 16);
        u32t p1 = (u32t)f2bf(acc[i][j][2] + bv) | ((u32t)f2bf(acc[i][j][3] + bv) << 16);
        u64t pk = (u64t)p0 | ((u64t)p1 << 32);
        *(u64t*)(vt + ((size_t)(b*NH + h)*64 + d)*NS + s0) = pk; // 4 consecutive s packed
      }
    }
  }
}

// ---------------- out GEMM: Y[8192,1024] = A(bf16) @ Wo^T(bf16) + bo, f32 out ----------------
__global__ __launch_bounds__(256) void out_gemm_kernel(
    const u16t* __restrict__ A, const u16t* __restrict__ Bt,
    const float* __restrict__ bias, float* __restrict__ Y)
{
  __shared__ u16t lds[2*4096];
  const int tid = threadIdx.x;
  const int l = tid & 63, w = tid >> 6;
  const int wr = w >> 1, wc = w & 1;
  const int mt = blockIdx.y, nt = blockIdx.x;
  f32x4 acc[4][4] = {};
  for (int ks = 0; ks < 32; ++ks){
    __syncthreads();
    #pragma unroll
    for (int p = 0; p < 2; ++p){
      const u16t* src = p ? Bt : A;
      int rb = (p ? nt : mt) * 128;
      #pragma unroll
      for (int ii = 0; ii < 2; ++ii){
        int c = tid + ii*256;
        int row = c >> 2, kc = c & 3;
        s16x8 v = *(const s16x8*)(src + (size_t)(rb + row)*1024 + ks*32 + kc*8);
        *(s16x8*)((char*)lds + p*8192 + ((row*64 + kc*16) ^ SWZ(row))) = v;
      }
    }
    __syncthreads();
    s16x8 af[4], bf[4];
    const int kb = (l >> 4) * 16;
    #pragma unroll
    for (int i = 0; i < 4; ++i){
      int row = wr*64 + i*16 + (l & 15);
      af[i] = *(const s16x8*)((char*)lds + ((row*64 + kb) ^ SWZ(row)));
    }
    #pragma unroll
    for (int j = 0; j < 4; ++j){
      int row = wc*64 + j*16 + (l & 15);
      bf[j] = *(const s16x8*)((char*)lds + 8192 + ((row*64 + kb) ^ SWZ(row)));
    }
    #pragma unroll
    for (int i = 0; i < 4; ++i)
      #pragma unroll
      for (int j = 0; j < 4; ++j)
        acc[i][j] = mfma16(af[i], bf[j], acc[i][j]);
  }
  #pragma unroll
  for (int j = 0; j < 4; ++j){
    int col = nt*128 + wc*64 + j*16 + (l & 15);
    float bv = bias[col];
    #pragma unroll
    for (int i = 0; i < 4; ++i){
      int tok0 = mt*128 + wr*64 + i*16 + (l >> 4)*4;
      float* dst = Y + (size_t)tok0*1024 + col;
      #pragma unroll
      for (int r = 0; r < 4; ++r) dst[(size_t)r*1024] = acc[i][j][r] + bv;
    }
  }
}

// ---------------- fused sparse attention: 1 WG = (bh, 16 q-rows), 2 blocks/CU ----------------
__global__ __launch_bounds__(256) void attn_kernel(
    const float* __restrict__ qbuf, const u16t* __restrict__ khi,
    const u16t* __restrict__ klo, const u16t* __restrict__ vtg,
    u16t* __restrict__ aout)
{
  extern __shared__ char smem[];
  char* Sb = smem;                 // 65536: scores->normalized weights [16][2048] bf16, swizzled
  char* KV = smem + 65536;         // 8192: K-hi / K-lo / V tile (64x64 bf16), time-shared

  const int tid = threadIdx.x;
  const int l = tid & 63, w = tid >> 6;
  int lid = ((blockIdx.x & 7) << 10) | (blockIdx.x >> 3); // XCD-chunked swizzle (8192%8==0)
  const int bh = lid >> 7, qt = lid & 127;
  const size_t kbase = (size_t)bh*NS*64;

  // Phase 0: Q fragments straight from global (swapped-QK: Q is the B operand).
  // lane: qrow = l&15, d-slice = c*32 + (l>>4)*8
  s16x8 qh[2], ql[2];
  {
    const float* qp = qbuf + ((size_t)bh*NS + qt*16 + (l & 15))*64;
    #pragma unroll
    for (int c = 0; c < 2; ++c){
      const float* p = qp + c*32 + (l>>4)*8;
      float4 va = *(const float4*)p;
      float4 vb = *(const float4*)(p + 4);
      float vv[8] = {va.x,va.y,va.z,va.w,vb.x,vb.y,vb.z,vb.w};
      #pragma unroll
      for (int e = 0; e < 8; ++e){
        u16t hh = f2bf(vv[e]);
        qh[c][e] = (short)hh;
        ql[c][e] = (short)f2bf(vv[e] - bf2f(hh));
      }
    }
  }

  // Phase 1: scores = (1/8) K (Q_h+Q_l)^T via mfma(K,Q): C[tok][qrow].
  // K hi and lo time-share the 8KB KV buffer.
  for (int kt = 0; kt < 32; ++kt){
    __syncthreads();
    #pragma unroll
    for (int ii = 0; ii < 2; ++ii){
      int idx = tid + ii*256;
      int tok = idx >> 3, part = idx & 7;
      s16x8 v = *(const s16x8*)(khi + kbase + (size_t)(kt*64 + tok)*64 + part*8);
      *(s16x8*)(KV + ((tok*128 + part*16) ^ SWZ(tok))) = v;
    }
    __syncthreads();
    f32x4 sacc = {};
    #pragma unroll
    for (int c = 0; c < 2; ++c){
      int tok = w*16 + (l & 15);
      s16x8 kf = *(const s16x8*)(KV + ((tok*128 + (c*32 + (l>>4)*8)*2) ^ SWZ(tok)));
      sacc = mfma16(kf, qh[c], sacc);
      sacc = mfma16(kf, ql[c], sacc);
    }
    __syncthreads();
    #pragma unroll
    for (int ii = 0; ii < 2; ++ii){
      int idx = tid + ii*256;
      int tok = idx >> 3, part = idx & 7;
      s16x8 v = *(const s16x8*)(klo + kbase + (size_t)(kt*64 + tok)*64 + part*8);
      *(s16x8*)(KV + ((tok*128 + part*16) ^ SWZ(tok))) = v;
    }
    __syncthreads();
    #pragma unroll
    for (int c = 0; c < 2; ++c){
      int tok = w*16 + (l & 15);
      s16x8 kf = *(const s16x8*)(KV + ((tok*128 + (c*32 + (l>>4)*8)*2) ^ SWZ(tok)));
      sacc = mfma16(kf, qh[c], sacc);
    }
    // write scores: lane holds 4 consecutive toks (C rows) for one qrow (C col)
    int qrow = l & 15;
    int t0 = w*16 + (l>>4)*4;
    u32t p0 = (u32t)f2bf(sacc[0]*0.125f) | ((u32t)f2bf(sacc[1]*0.125f) << 16);
    u32t p1 = (u32t)f2bf(sacc[2]*0.125f) | ((u32t)f2bf(sacc[3]*0.125f) << 16);
    u64t pk = (u64t)p0 | ((u64t)p1 << 32);
    *(u64t*)(Sb + ((qrow*4096 + (kt*64 + t0)*2) ^ SWZ(qrow))) = pk;
  }
  __syncthreads();

  // Phase 2: per-row exact top-204 threshold (register radix-select, no atomics)
  // + weights pre-scaled by 1/Z written back into Sb. Wave w owns rows w*4..w*4+3.
  for (int rr = 0; rr < 4; ++rr){
    int row = w*4 + rr;
    int rswz = SWZ(row);
    u16t kx[4][8];
    u32t lmax = 0;
    #pragma unroll
    for (int i = 0; i < 4; ++i){
      s16x8 v = *(const s16x8*)(Sb + ((row*4096 + i*1024 + l*16) ^ rswz));
      #pragma unroll
      for (int e = 0; e < 8; ++e){
        u16t kk = mono16((u16t)v[e]);
        kx[i][e] = kk;
        lmax = lmax > (u32t)kk ? lmax : (u32t)kk;
      }
    }
    #pragma unroll
    for (int o = 32; o; o >>= 1){
      u32t ot = (u32t)__shfl_xor((int)lmax, o);
      lmax = lmax > ot ? lmax : ot;
    }
    float mx = fmaxf(bf2f(unmono16((u16t)lmax)), 0.0f); // max(sparse_scores)

    // MSB-first 4x4-bit radix select for the 204th largest key
    u32t pfx = 0; int t = TOPK; int m = 0;
    #pragma unroll
    for (int pass = 0; pass < 4; ++pass){
      int sh = 12 - pass*4;
      u64t c0 = 0, c1 = 0;   // 8-bit fields x8 (per-lane counts, max 32)
      #pragma unroll
      for (int i = 0; i < 4; ++i)
        #pragma unroll
        for (int e = 0; e < 8; ++e){
          u32t x = (u32t)kx[i][e];
          u32t dig = (x >> sh) & 15u;
          u32t cand = (((x ^ pfx) >> (sh + 4)) == 0u) ? 1u : 0u;
          u64t inc = (u64t)cand << ((dig & 7) * 8);
          c0 += (dig < 8) ? inc : (u64t)0;
          c1 += (dig < 8) ? (u64t)0 : inc;
        }
      // widen to 16-bit fields (wave total max 2048)
      u64t f0 = c0 & 0x00FF00FF00FF00FFull;        // digits 0,2,4,6
      u64t f1 = (c0 >> 8) & 0x00FF00FF00FF00FFull; // digits 1,3,5,7
      u64t f2 = c1 & 0x00FF00FF00FF00FFull;        // digits 8,10,12,14
      u64t f3 = (c1 >> 8) & 0x00FF00FF00FF00FFull; // digits 9,11,13,15
      #pragma unroll
      for (int o = 32; o; o >>= 1){
        f0 += sxor64(f0, o); f1 += sxor64(f1, o);
        f2 += sxor64(f2, o); f3 += sxor64(f3, o);
      }
      // scan digits 15..0 (all lanes uniform)
      u32t cum = 0, vstar = 0, cntv = 0; int tnew = t; int found = 0;
      #pragma unroll
      for (int v = 15; v >= 0; --v){
        u64t src = (v < 8) ? ((v & 1) ? f1 : f0) : ((v & 1) ? f3 : f2);
        u32t c = (u32t)(src >> (((v & 7) >> 1) * 16)) & 0xFFFFu;
        if (!found && (u32t)t > cum && (u32t)t <= cum + c){
          vstar = (u32t)v; cntv = c; tnew = t - (int)cum; found = 1;
        }
        cum += c;
      }
      pfx |= vstar << sh; t = tnew; m = (int)cntv;
    }
    u16t kbt = (u16t)pfx;
    int rk = t;               // 1-based rank within the m equal-keyed entries

    if (rk < m){ // exact f32 order inside the threshold bucket
      float cv = -3.0e38f;    // lane i holds candidate i's f32 score
      int cnt = 0;
      #pragma unroll
      for (int i = 0; i < 4; ++i)
        #pragma unroll
        for (int e = 0; e < 8; ++e){
          u64t mask = __ballot(kx[i][e] == kbt);
          while (mask && cnt < 64){
            int j = __ffsll((unsigned long long)mask) - 1;
            mask &= mask - 1;
            int tok = i*512 + j*8 + e;
            float qv = qbuf[((size_t)bh*NS + qt*16 + row)*64 + l];
            size_t g = kbase + (size_t)tok*64 + l;
            float kv = bf2f(khi[g]) + bf2f(klo[g]);
            float pr = qv * kv;
            #pragma unroll
            for (int o = 32; o; o >>= 1) pr += __shfl_xor(pr, o);
            if (l == cnt) cv = pr * 0.125f;
            cnt++;
          }
        }
      float x = cv;
      int gt = 0, eq = 0;
      for (int jj = 0; jj < cnt; ++jj){
        float vj = __shfl(x, jj);
        gt += (vj > x);
        eq += (vj == x);
      }
      bool ok = (l < cnt) && (gt < rk) && (rk <= gt + eq);
      u64t bm2 = __ballot(ok);
      int s2 = __ffsll((unsigned long long)bm2) - 1;
      float tval = __shfl(x, s2);        // exact rk-th largest in bucket
      int c2 = 0;
      #pragma unroll
      for (int i = 0; i < 4; ++i)
        #pragma unroll
        for (int e = 0; e < 8; ++e){
          u64t mask = __ballot(kx[i][e] == kbt);
          while (mask && c2 < 64){
            int j = __ffsll((unsigned long long)mask) - 1;
            mask &= mask - 1;
            float vv2 = __shfl(cv, c2);
            c2++;
            if (l == j && vv2 < tval) kx[i][e] = 0; // demote below-threshold members
          }
        }
    }
    // weights: kept -> exp(s-mx); masked -> exp(-mx); prescale by 1/Z; write back bf16
    float em = __expf(-mx);
    float zs = 0.f;
    float wsv[4][8];
    #pragma unroll
    for (int i = 0; i < 4; ++i)
      #pragma unroll
      for (int e = 0; e < 8; ++e){
        u16t kk = kx[i][e];
        float wgt = (kk >= kbt) ? __expf(bf2f(unmono16(kk)) - mx) : em;
        zs += wgt;
        wsv[i][e] = wgt;
      }
    #pragma unroll
    for (int o = 32; o; o >>= 1) zs += __shfl_xor(zs, o);
    float zinv = 1.0f / (zs + 1e-9f);
    #pragma unroll
    for (int i = 0; i < 4; ++i){
      s16x8 wv;
      #pragma unroll
      for (int e = 0; e < 8; ++e) wv[e] = (short)f2bf(wsv[i][e] * zinv);
      *(s16x8*)(Sb + ((row*4096 + i*1024 + l*16) ^ rswz)) = wv;
    }
  }

  // Phase 3: PV via mfma(V^T, W): C[d][qrow]. Wave w owns d-block w*16..w*16+15.
  f32x4 pacc = {};
  for (int kt = 0; kt < 32; ++kt){
    __syncthreads();
    #pragma unroll
    for (int ii = 0; ii < 2; ++ii){
      int idx = tid + ii*256;
      int d = idx >> 3, part = idx & 7;
      s16x8 v = *(const s16x8*)(vtg + ((size_t)bh*64 + d)*NS + kt*64 + part*8);
      *(s16x8*)(KV + ((d*128 + part*16) ^ SWZ(d))) = v;
    }
    __syncthreads();
    #pragma unroll
    for (int c = 0; c < 2; ++c){
      int vd = w*16 + (l & 15);
      s16x8 vf = *(const s16x8*)(KV + ((vd*128 + (c*32 + (l>>4)*8)*2) ^ SWZ(vd)));
      int qrow = l & 15;
      s16x8 wf = *(const s16x8*)(Sb + ((qrow*4096 + (kt*64 + c*32 + (l>>4)*8)*2) ^ SWZ(qrow)));
      pacc = mfma16(vf, wf, pacc);
    }
  }
  // epilogue: weights already carry 1/Z; store attn-out bf16 [B][S][H*64]
  {
    int qrow = l & 15;
    int tok = qt*16 + qrow;
    int b = bh >> 4, h = bh & 15;
    int d0 = w*16 + (l>>4)*4;
    u32t p0 = (u32t)f2bf(pacc[0]) | ((u32t)f2bf(pacc[1]) << 16);
    u32t p1 = (u32t)f2bf(pacc[2]) | ((u32t)f2bf(pacc[3]) << 16);
    *(u64t*)(aout + ((size_t)(b*NS + tok)*1024 + h*64 + d0)) = (u64t)p0 | ((u64t)p1 << 32);
  }
}

// ---------------- workspace layout ----------------
#define O_XHI  ((size_t)0)
#define O_XLO  (O_XHI + (size_t)NTOK*ND*2)
#define O_WQH  (O_XLO + (size_t)NTOK*ND*2)
#define O_WQL  (O_WQH + (size_t)3072*1024*2)
#define O_WOB  (O_WQL + (size_t)3072*1024*2)
#define O_Q    (O_WOB + (size_t)1024*1024*2)
#define O_KHI  (O_Q   + (size_t)NBH*NS*64*4)
#define O_KLO  (O_KHI + (size_t)NBH*NS*64*2)
#define O_VT   (O_KLO + (size_t)NBH*NS*64*2)
#define O_AOUT O_XHI   /* alias: x_hi dead after QKV GEMM */
#define WS_NEED (O_VT + (size_t)NBH*NS*64*2)

extern "C" void kernel_launch(void* const* d_in, const int* in_sizes, int n_in,
                              void* d_out, int out_size, void* d_ws, size_t ws_size,
                              hipStream_t stream)
{
  (void)in_sizes; (void)n_in; (void)out_size;
  const float* x    = (const float*)d_in[0];
  const float* Wqkv = (const float*)d_in[1];
  const float* bqkv = (const float*)d_in[2];
  const float* Wo   = (const float*)d_in[3];
  const float* bo   = (const float*)d_in[4];
  float* Y = (float*)d_out;
  char* ws = (char*)d_ws;
  if (ws_size < WS_NEED) return;

  u16t* xhi  = (u16t*)(ws + O_XHI);
  u16t* xlo  = (u16t*)(ws + O_XLO);
  u16t* wqh  = (u16t*)(ws + O_WQH);
  u16t* wql  = (u16t*)(ws + O_WQL);
  u16t* wob  = (u16t*)(ws + O_WOB);
  float* qbuf = (float*)(ws + O_Q);
  u16t* khi  = (u16t*)(ws + O_KHI);
  u16t* klo  = (u16t*)(ws + O_KLO);
  u16t* vt   = (u16t*)(ws + O_VT);
  u16t* aout = (u16t*)(ws + O_AOUT);

  hipFuncSetAttribute((const void*)attn_kernel,
                      hipFuncAttributeMaxDynamicSharedMemorySize, 73728);

  split_pair_kernel<<<(NTOK*ND/4)/256, 256, 0, stream>>>(x, xhi, xlo, NTOK*ND/4);
  split_pair_kernel<<<(3072*1024/4)/256, 256, 0, stream>>>(Wqkv, wqh, wql, 3072*1024/4);
  cvt_kernel<<<(1024*1024/4)/256, 256, 0, stream>>>(Wo, wob, 1024*1024/4);
  qkv_gemm_kernel<<<dim3(24, 64), 256, 0, stream>>>(xhi, xlo, wqh, wql, bqkv,
                                                    qbuf, khi, klo, vt);
  attn_kernel<<<8192, 256, 73728, stream>>>(qbuf, khi, klo, vt, aout);
  out_gemm_kernel<<<dim3(8, 64), 256, 0, stream>>>(aout, wob, bo, Y);
}

// Round 3
// 1399.176 us; speedup vs baseline: 1.3364x; 1.2157x over previous
//
#include <hip/hip_runtime.h>
#include <stdint.h>

typedef unsigned short u16t;
typedef unsigned int   u32t;
typedef unsigned long long u64t;
typedef __attribute__((ext_vector_type(4))) float f32x4;
typedef __attribute__((ext_vector_type(8))) short s16x8;
typedef __attribute__((ext_vector_type(4))) u32t u32x4;
typedef __attribute__((ext_vector_type(2))) u32t u32x2;

#define NB 4
#define NS 2048
#define ND 1024
#define NH 16
#define NBH 64
#define NTOK 8192
#define TOPK 204
#define KSCALE 184.6649652337873f   /* 1024*log2(e)/8 */

__device__ __forceinline__ u16t f2bf(float f){
  u32t u = __builtin_bit_cast(u32t, f);
  u32t r = (u + 0x7FFFu + ((u >> 16) & 1u)) >> 16;
  return (u16t)r;
}
__device__ __forceinline__ float bf2f(u16t h){
  u32t u = ((u32t)h) << 16;
  return __builtin_bit_cast(float, u);
}
__device__ __forceinline__ f32x4 mfma16(s16x8 a, s16x8 b, f32x4 c){
  return __builtin_amdgcn_mfma_f32_16x16x32_bf16(a, b, c, 0, 0, 0);
}
__device__ __forceinline__ u32t pk_bf16(float a, float b){
  u32t r;
  asm volatile("v_cvt_pk_bf16_f32 %0, %1, %2" : "=v"(r) : "v"(a), "v"(b));
  return r;
}
__device__ __forceinline__ u32t mkkey(float s){
  float kf = fmaf(s, KSCALE, 32768.0f);
  kf = fminf(fmaxf(kf, 0.0f), 65535.0f);
  return (u32t)rintf(kf);
}

#define SWZ(r) (((r) & 7) << 4)

// ---------------- split / convert kernels ----------------
__global__ __launch_bounds__(256) void split_pair_kernel(const float* __restrict__ src,
    u16t* __restrict__ hi, u16t* __restrict__ lo, int n4){
  int i = blockIdx.x * 256 + threadIdx.x;
  if (i >= n4) return;
  float4 v = ((const float4*)src)[i];
  float a0=v.x, a1=v.y, a2=v.z, a3=v.w;
  u16t h0=f2bf(a0), h1=f2bf(a1), h2=f2bf(a2), h3=f2bf(a3);
  u16t l0=f2bf(a0-bf2f(h0)), l1=f2bf(a1-bf2f(h1)), l2=f2bf(a2-bf2f(h2)), l3=f2bf(a3-bf2f(h3));
  ((u64t*)hi)[i] = (u64t)h0 | ((u64t)h1<<16) | ((u64t)h2<<32) | ((u64t)h3<<48);
  ((u64t*)lo)[i] = (u64t)l0 | ((u64t)l1<<16) | ((u64t)l2<<32) | ((u64t)l3<<48);
}

__global__ __launch_bounds__(256) void cvt_kernel(const float* __restrict__ src,
    u16t* __restrict__ dst, int n4){
  int i = blockIdx.x * 256 + threadIdx.x;
  if (i >= n4) return;
  float4 v = ((const float4*)src)[i];
  u16t h0=f2bf(v.x), h1=f2bf(v.y), h2=f2bf(v.z), h3=f2bf(v.w);
  ((u64t*)dst)[i] = (u64t)h0 | ((u64t)h1<<16) | ((u64t)h2<<32) | ((u64t)h3<<48);
}

// ---------------- QKV GEMM: C[8192,3072] = (xh+xl)(Wh+Wl)^T + b, split 3-pass ----------------
__global__ __launch_bounds__(256) void qkv_gemm_kernel(
    const u16t* __restrict__ Ah, const u16t* __restrict__ Al,
    const u16t* __restrict__ Bh, const u16t* __restrict__ Bl,
    const float* __restrict__ bias,
    float* __restrict__ qout, u16t* __restrict__ khi, u16t* __restrict__ klo,
    u16t* __restrict__ vt)
{
  __shared__ u16t lds[4*4096];
  const int tid = threadIdx.x;
  const int l = tid & 63, w = tid >> 6;
  const int wr = w >> 1, wc = w & 1;
  const int mt = blockIdx.y, nt = blockIdx.x;
  f32x4 acc[4][4] = {};
  for (int ks = 0; ks < 32; ++ks){
    __syncthreads();
    #pragma unroll
    for (int p = 0; p < 4; ++p){
      const u16t* src = (p==0) ? Ah : (p==1) ? Al : (p==2) ? Bh : Bl;
      int rb = ((p < 2) ? mt : nt) * 128;
      #pragma unroll
      for (int ii = 0; ii < 2; ++ii){
        int c = tid + ii*256;
        int row = c >> 2, kc = c & 3;
        s16x8 v = *(const s16x8*)(src + (size_t)(rb + row)*1024 + ks*32 + kc*8);
        *(s16x8*)((char*)lds + p*8192 + ((row*64 + kc*16) ^ SWZ(row))) = v;
      }
    }
    __syncthreads();
    s16x8 afh[4], afl[4], bfh[4], bfl[4];
    const int kb = (l >> 4) * 16;
    #pragma unroll
    for (int i = 0; i < 4; ++i){
      int row = wr*64 + i*16 + (l & 15);
      int off = (row*64 + kb) ^ SWZ(row);
      afh[i] = *(const s16x8*)((char*)lds + off);
      afl[i] = *(const s16x8*)((char*)lds + 8192 + off);
    }
    #pragma unroll
    for (int j = 0; j < 4; ++j){
      int row = wc*64 + j*16 + (l & 15);
      int off = (row*64 + kb) ^ SWZ(row);
      bfh[j] = *(const s16x8*)((char*)lds + 16384 + off);
      bfl[j] = *(const s16x8*)((char*)lds + 24576 + off);
    }
    #pragma unroll
    for (int i = 0; i < 4; ++i)
      #pragma unroll
      for (int j = 0; j < 4; ++j){
        acc[i][j] = mfma16(afh[i], bfh[j], acc[i][j]);
        acc[i][j] = mfma16(afh[i], bfl[j], acc[i][j]);
        acc[i][j] = mfma16(afl[i], bfh[j], acc[i][j]);
      }
  }
  #pragma unroll
  for (int j = 0; j < 4; ++j){
    int col = nt*128 + wc*64 + j*16 + (l & 15);
    float bv = bias[col];
    #pragma unroll
    for (int i = 0; i < 4; ++i){
      int tok0 = mt*128 + wr*64 + i*16 + (l >> 4)*4;
      int b = tok0 >> 11;
      int s0 = tok0 & 2047;
      if (col < 1024){
        int h = col >> 6, d = col & 63;
        float* dst = qout + ((size_t)(b*NH + h)*NS + s0)*64 + d;
        #pragma unroll
        for (int r = 0; r < 4; ++r) dst[(size_t)r*64] = acc[i][j][r] + bv;
      } else if (col < 2048){
        int ch = col - 1024; int h = ch >> 6, d = ch & 63;
        size_t idx = ((size_t)(b*NH + h)*NS + s0)*64 + d;
        #pragma unroll
        for (int r = 0; r < 4; ++r){
          float v0 = acc[i][j][r] + bv;
          u16t hh = f2bf(v0);
          khi[idx + (size_t)r*64] = hh;
          klo[idx + (size_t)r*64] = f2bf(v0 - bf2f(hh));
        }
      } else {
        int ch = col - 2048; int h = ch >> 6, d = ch & 63;
        u32t p0 = (u32t)f2bf(acc[i][j][0] + bv) | ((u32t)f2bf(acc[i][j][1] + bv) << 16);
        u32t p1 = (u32t)f2bf(acc[i][j][2] + bv) | ((u32t)f2bf(acc[i][j][3] + bv) << 16);
        u64t pk = (u64t)p0 | ((u64t)p1 << 32);
        *(u64t*)(vt + ((size_t)(b*NH + h)*64 + d)*NS + s0) = pk;
      }
    }
  }
}

// ---------------- out GEMM ----------------
__global__ __launch_bounds__(256) void out_gemm_kernel(
    const u16t* __restrict__ A, const u16t* __restrict__ Bt,
    const float* __restrict__ bias, float* __restrict__ Y)
{
  __shared__ u16t lds[2*4096];
  const int tid = threadIdx.x;
  const int l = tid & 63, w = tid >> 6;
  const int wr = w >> 1, wc = w & 1;
  const int mt = blockIdx.y, nt = blockIdx.x;
  f32x4 acc[4][4] = {};
  for (int ks = 0; ks < 32; ++ks){
    __syncthreads();
    #pragma unroll
    for (int p = 0; p < 2; ++p){
      const u16t* src = p ? Bt : A;
      int rb = (p ? nt : mt) * 128;
      #pragma unroll
      for (int ii = 0; ii < 2; ++ii){
        int c = tid + ii*256;
        int row = c >> 2, kc = c & 3;
        s16x8 v = *(const s16x8*)(src + (size_t)(rb + row)*1024 + ks*32 + kc*8);
        *(s16x8*)((char*)lds + p*8192 + ((row*64 + kc*16) ^ SWZ(row))) = v;
      }
    }
    __syncthreads();
    s16x8 af[4], bf[4];
    const int kb = (l >> 4) * 16;
    #pragma unroll
    for (int i = 0; i < 4; ++i){
      int row = wr*64 + i*16 + (l & 15);
      af[i] = *(const s16x8*)((char*)lds + ((row*64 + kb) ^ SWZ(row)));
    }
    #pragma unroll
    for (int j = 0; j < 4; ++j){
      int row = wc*64 + j*16 + (l & 15);
      bf[j] = *(const s16x8*)((char*)lds + 8192 + ((row*64 + kb) ^ SWZ(row)));
    }
    #pragma unroll
    for (int i = 0; i < 4; ++i)
      #pragma unroll
      for (int j = 0; j < 4; ++j)
        acc[i][j] = mfma16(af[i], bf[j], acc[i][j]);
  }
  #pragma unroll
  for (int j = 0; j < 4; ++j){
    int col = nt*128 + wc*64 + j*16 + (l & 15);
    float bv = bias[col];
    #pragma unroll
    for (int i = 0; i < 4; ++i){
      int tok0 = mt*128 + wr*64 + i*16 + (l >> 4)*4;
      float* dst = Y + (size_t)tok0*1024 + col;
      #pragma unroll
      for (int r = 0; r < 4; ++r) dst[(size_t)r*1024] = acc[i][j][r] + bv;
    }
  }
}

// ---------------- A: scores -> u16 keys [bhl][q][tok] ----------------
// grid (16 qtiles, gbh); block 256 = 4 waves; wave = 32 q rows.
// swapped mfma(K, Q): C[tok][q]; lane: col q = l&15, rows = 4 consecutive toks.
__global__ __launch_bounds__(256) void score_kernel(
    const float* __restrict__ qbuf, const u16t* __restrict__ khi,
    const u16t* __restrict__ klo, u16t* __restrict__ keys, int bh0)
{
  const int tid = threadIdx.x;
  const int l = tid & 63, w = tid >> 6;
  const int bhl = blockIdx.y, bh = bh0 + bhl;
  const int q0 = blockIdx.x * 128 + w * 32;

  s16x8 qh[2][2], ql[2][2];
  #pragma unroll
  for (int qf = 0; qf < 2; ++qf){
    const float* qp = qbuf + ((size_t)bh*NS + q0 + qf*16 + (l & 15))*64 + (l >> 4)*8;
    #pragma unroll
    for (int kk = 0; kk < 2; ++kk){
      float4 va = *(const float4*)(qp + kk*32);
      float4 vb = *(const float4*)(qp + kk*32 + 4);
      float vv[8] = {va.x,va.y,va.z,va.w,vb.x,vb.y,vb.z,vb.w};
      #pragma unroll
      for (int e = 0; e < 8; ++e){
        u16t hh = f2bf(vv[e]);
        qh[qf][kk][e] = (short)hh;
        ql[qf][kk][e] = (short)f2bf(vv[e] - bf2f(hh));
      }
    }
  }

  const size_t kbase = (size_t)bh*NS*64 + (l >> 4)*8;
  const size_t rowb0 = (size_t)(bhl*NS + q0 + (l & 15));
  s16x8 nh0, nh1, nl0, nl1;
  {
    size_t a = kbase + (size_t)(l & 15)*64;
    nh0 = *(const s16x8*)(khi + a);
    nh1 = *(const s16x8*)(khi + a + 32);
    nl0 = *(const s16x8*)(klo + a);
    nl1 = *(const s16x8*)(klo + a + 32);
  }
  for (int it = 0; it < 128; ++it){
    s16x8 h0 = nh0, h1 = nh1, g0 = nl0, g1 = nl1;
    if (it + 1 < 128){
      size_t a = kbase + (size_t)((it+1)*16 + (l & 15))*64;
      nh0 = *(const s16x8*)(khi + a);
      nh1 = *(const s16x8*)(khi + a + 32);
      nl0 = *(const s16x8*)(klo + a);
      nl1 = *(const s16x8*)(klo + a + 32);
    }
    const int tstore = it*16 + (l >> 4)*4;
    #pragma unroll
    for (int qf = 0; qf < 2; ++qf){
      f32x4 acc = {};
      acc = mfma16(h0, qh[qf][0], acc);
      acc = mfma16(h1, qh[qf][1], acc);
      acc = mfma16(h0, ql[qf][0], acc);
      acc = mfma16(h1, ql[qf][1], acc);
      acc = mfma16(g0, qh[qf][0], acc);
      acc = mfma16(g1, qh[qf][1], acc);
      u32t k0 = mkkey(acc[0]), k1 = mkkey(acc[1]);
      u32t k2 = mkkey(acc[2]), k3 = mkkey(acc[3]);
      u32x2 pk;
      pk[0] = k0 | (k1 << 16);
      pk[1] = k2 | (k3 << 16);
      *(u32x2*)(keys + (rowb0 + qf*16)*NS + tstore) = pk;
    }
  }
}

// ---------------- B: exact top-204 threshold + softmax weights (in-place) ----------------
// 1 wave per row; 32 keys/lane in regs; binary search on key value.
__global__ __launch_bounds__(256) void select_kernel(u16t* __restrict__ keys)
{
  const int tid = threadIdx.x;
  const int l = tid & 63, w = tid >> 6;
  const size_t rid = (size_t)blockIdx.x*4 + w;
  u32t* p = (u32t*)keys + rid*1024 + l*4;

  u32t ku[16], kl[16];
  #pragma unroll
  for (int i = 0; i < 4; ++i){
    u32x4 v = *(const u32x4*)(p + i*256);
    #pragma unroll
    for (int j = 0; j < 4; ++j){ ku[i*4+j] = v[j]; kl[i*4+j] = v[j] << 16; }
  }
  // row max key
  u32t mh = 0, ml = 0;
  #pragma unroll
  for (int i = 0; i < 16; ++i){
    mh = mh > ku[i] ? mh : ku[i];
    ml = ml > kl[i] ? ml : kl[i];
  }
  u32t km = mh >> 16; u32t m2 = ml >> 16;
  km = km > m2 ? km : m2;
  #pragma unroll
  for (int o = 32; o; o >>= 1){
    u32t t = (u32t)__shfl_xor((int)km, o);
    km = km > t ? km : t;
  }

  // count of keys < mid across row (wave-reduced)
  #define CNTLT(mid, out) {                                   \
    u32t mm = (mid) << 16;                                    \
    u32t c0=0,c1=0,c2=0,c3=0;                                 \
    _Pragma("unroll")                                         \
    for (int i = 0; i < 16; i += 4){                          \
      c0 += (ku[i  ] < mm) + (kl[i  ] < mm);                  \
      c1 += (ku[i+1] < mm) + (kl[i+1] < mm);                  \
      c2 += (ku[i+2] < mm) + (kl[i+2] < mm);                  \
      c3 += (ku[i+3] < mm) + (kl[i+3] < mm);                  \
    }                                                         \
    u32t cc = (c0+c1)+(c2+c3);                                \
    _Pragma("unroll")                                         \
    for (int o = 32; o; o >>= 1) cc += (u32t)__shfl_xor((int)cc, o); \
    out = cc;                                                 \
  }

  u32t lo, hi, cseed;
  CNTLT(32768u, cseed);
  if (2048u - cseed >= (u32t)TOPK){ lo = 32768u; hi = km; }
  else                            { lo = 0u;     hi = 32767u; }
  while (lo < hi){
    u32t mid = (lo + hi + 1u) >> 1;
    u32t c; CNTLT(mid, c);
    if (2048u - c >= (u32t)TOPK) lo = mid; else hi = mid - 1u;
  }
  const u32t kbt = lo;

  // weights: kept -> 2^((k-kmx)/1024); masked -> 2^((32768-kmx)/1024); prescale 1/Z
  const u32t kmxe = km < 32768u ? 32768u : km;
  const float dsh = -(float)kmxe * 0.0009765625f;
  const float em = exp2f(fmaf((float)32768u, 0.0009765625f, dsh));
  float wv[32];
  float zs = 0.0f;
  #pragma unroll
  for (int i = 0; i < 16; ++i){
    u32t x0 = ku[i] & 0xFFFFu, x1 = ku[i] >> 16;
    float e0 = exp2f(fmaf((float)x0, 0.0009765625f, dsh));
    float e1 = exp2f(fmaf((float)x1, 0.0009765625f, dsh));
    wv[2*i]   = (x0 >= kbt) ? e0 : em;
    wv[2*i+1] = (x1 >= kbt) ? e1 : em;
    zs += wv[2*i] + wv[2*i+1];
  }
  #pragma unroll
  for (int o = 32; o; o >>= 1) zs += __shfl_xor(zs, o);
  const float zinv = 1.0f / (zs + 1e-9f);
  #pragma unroll
  for (int i = 0; i < 4; ++i){
    u32x4 o;
    #pragma unroll
    for (int j = 0; j < 4; ++j){
      int e = 2*(i*4+j);
      o[j] = pk_bf16(wv[e]*zinv, wv[e+1]*zinv);
    }
    *(u32x4*)(p + i*256) = o;
  }
}

// ---------------- C: PV — out[q][d] = W[q][tok] x V[tok][d] ----------------
// grid (32, gbh); block 256 = 4 waves; wave = 16 q rows, all 64 d.
__global__ __launch_bounds__(256) void pv_kernel(
    const u16t* __restrict__ wts, const u16t* __restrict__ vtg,
    u16t* __restrict__ aout, int bh0)
{
  const int tid = threadIdx.x;
  const int l = tid & 63, w = tid >> 6;
  const int bhl = blockIdx.y, bh = bh0 + bhl;
  const int q16 = blockIdx.x*64 + w*16;
  const u16t* wp = wts + ((size_t)(bhl*NS) + q16 + (l & 15))*NS + (l >> 4)*8;
  const u16t* vp = vtg + ((size_t)bh*64 + (l & 15))*NS + (l >> 4)*8;
  f32x4 acc[4] = {};
  for (int kt = 0; kt < 64; ++kt){
    s16x8 wf = *(const s16x8*)(wp + kt*32);
    #pragma unroll
    for (int db = 0; db < 4; ++db){
      s16x8 vf = *(const s16x8*)(vp + (size_t)db*16*NS + kt*32);
      acc[db] = mfma16(wf, vf, acc[db]);
    }
  }
  const int b = bh >> 4, h = bh & 15;
  #pragma unroll
  for (int db = 0; db < 4; ++db)
    #pragma unroll
    for (int r = 0; r < 4; ++r){
      int q = q16 + (l >> 4)*4 + r;
      aout[((size_t)(b*NS + q))*1024 + h*64 + db*16 + (l & 15)] = f2bf(acc[db][r]);
    }
}

// ---------------- workspace layout ----------------
#define O_XHI  ((size_t)0)
#define O_XLO  (O_XHI + (size_t)NTOK*ND*2)
#define O_WQH  (O_XLO + (size_t)NTOK*ND*2)
#define O_WQL  (O_WQH + (size_t)3072*1024*2)
#define O_WOB  (O_WQL + (size_t)3072*1024*2)
#define O_Q    (O_WOB + (size_t)1024*1024*2)
#define O_KHI  (O_Q   + (size_t)NBH*NS*64*4)
#define O_KLO  (O_KHI + (size_t)NBH*NS*64*2)
#define O_VT   (O_KLO + (size_t)NBH*NS*64*2)
#define O_AOUT (O_VT  + (size_t)NBH*NS*64*2)
#define AOUT_SZ ((size_t)NTOK*ND*2)
#define O_KEYS (O_AOUT + AOUT_SZ)
#define PER_BH ((size_t)NS*NS*2)

extern "C" void kernel_launch(void* const* d_in, const int* in_sizes, int n_in,
                              void* d_out, int out_size, void* d_ws, size_t ws_size,
                              hipStream_t stream)
{
  (void)in_sizes; (void)n_in; (void)out_size;
  const float* x    = (const float*)d_in[0];
  const float* Wqkv = (const float*)d_in[1];
  const float* bqkv = (const float*)d_in[2];
  const float* Wo   = (const float*)d_in[3];
  const float* bo   = (const float*)d_in[4];
  float* Y = (float*)d_out;
  char* ws = (char*)d_ws;

  u16t* xhi  = (u16t*)(ws + O_XHI);
  u16t* xlo  = (u16t*)(ws + O_XLO);
  u16t* wqh  = (u16t*)(ws + O_WQH);
  u16t* wql  = (u16t*)(ws + O_WQL);
  u16t* wob  = (u16t*)(ws + O_WOB);
  float* qbuf = (float*)(ws + O_Q);
  u16t* khi  = (u16t*)(ws + O_KHI);
  u16t* klo  = (u16t*)(ws + O_KLO);
  u16t* vt   = (u16t*)(ws + O_VT);

  // adaptive scratch for keys/weights + aout placement
  u16t* keysp; u16t* aoutp; int gbh;
  if (ws_size >= O_KEYS + 2*PER_BH){
    aoutp = (u16t*)(ws + O_AOUT);
    keysp = (u16t*)(ws + O_KEYS);
    size_t avail = ws_size - O_KEYS;
    gbh = 64;
    while ((size_t)gbh * PER_BH > avail) gbh >>= 1;
  } else if (ws_size >= O_KEYS){
    aoutp = (u16t*)(ws + O_AOUT);
    keysp = (u16t*)(ws + O_XHI);   // xhi+xlo dead after qkv_gemm: 32 MB
    gbh = 4;
  } else if (ws_size >= O_AOUT){
    aoutp = (u16t*)(ws + O_XLO);   // alias xlo
    keysp = (u16t*)(ws + O_XHI);   // 16 MB
    gbh = 2;
  } else {
    return;
  }

  split_pair_kernel<<<(NTOK*ND/4)/256, 256, 0, stream>>>(x, xhi, xlo, NTOK*ND/4);
  split_pair_kernel<<<(3072*1024/4)/256, 256, 0, stream>>>(Wqkv, wqh, wql, 3072*1024/4);
  cvt_kernel<<<(1024*1024/4)/256, 256, 0, stream>>>(Wo, wob, 1024*1024/4);
  qkv_gemm_kernel<<<dim3(24, 64), 256, 0, stream>>>(xhi, xlo, wqh, wql, bqkv,
                                                    qbuf, khi, klo, vt);
  for (int bh0 = 0; bh0 < NBH; bh0 += gbh){
    score_kernel<<<dim3(16, gbh), 256, 0, stream>>>(qbuf, khi, klo, keysp, bh0);
    select_kernel<<<dim3(gbh*NS/4), 256, 0, stream>>>(keysp);
    pv_kernel<<<dim3(32, gbh), 256, 0, stream>>>(keysp, vt, aoutp, bh0);
  }
  out_gemm_kernel<<<dim3(8, 64), 256, 0, stream>>>(aoutp, wob, bo, Y);
}

// Round 4
// 1225.519 us; speedup vs baseline: 1.5258x; 1.1417x over previous
//
#include <hip/hip_runtime.h>
#include <stdint.h>

typedef unsigned short u16t;
typedef unsigned int   u32t;
typedef unsigned long long u64t;
typedef __attribute__((ext_vector_type(4))) float f32x4;
typedef __attribute__((ext_vector_type(8))) short s16x8;
typedef __attribute__((ext_vector_type(4))) u32t u32x4;

#define NB 4
#define NS 2048
#define ND 1024
#define NH 16
#define NBH 64
#define NTOK 8192
#define TOPK 204
#define KSCALE 184.6649652337873f   /* 1024*log2(e)/8 */

__device__ __forceinline__ u16t f2bf(float f){
  u32t u = __builtin_bit_cast(u32t, f);
  u32t r = (u + 0x7FFFu + ((u >> 16) & 1u)) >> 16;
  return (u16t)r;
}
__device__ __forceinline__ float bf2f(u16t h){
  u32t u = ((u32t)h) << 16;
  return __builtin_bit_cast(float, u);
}
__device__ __forceinline__ f32x4 mfma16(s16x8 a, s16x8 b, f32x4 c){
  return __builtin_amdgcn_mfma_f32_16x16x32_bf16(a, b, c, 0, 0, 0);
}
__device__ __forceinline__ u32t pk_bf16(float a, float b){
  u32t r;
  asm volatile("v_cvt_pk_bf16_f32 %0, %1, %2" : "=v"(r) : "v"(a), "v"(b));
  return r;
}
__device__ __forceinline__ u32t mkkey(float s){
  float kf = fmaf(s, KSCALE, 32768.0f);
  kf = fminf(fmaxf(kf, 0.0f), 65535.0f);
  return (u32t)rintf(kf);
}

#define SWZ(r) (((r) & 7) << 4)

// ---------------- split / convert kernels ----------------
__global__ __launch_bounds__(256) void split_pair_kernel(const float* __restrict__ src,
    u16t* __restrict__ hi, u16t* __restrict__ lo, int n4){
  int i = blockIdx.x * 256 + threadIdx.x;
  if (i >= n4) return;
  float4 v = ((const float4*)src)[i];
  float a0=v.x, a1=v.y, a2=v.z, a3=v.w;
  u16t h0=f2bf(a0), h1=f2bf(a1), h2=f2bf(a2), h3=f2bf(a3);
  u16t l0=f2bf(a0-bf2f(h0)), l1=f2bf(a1-bf2f(h1)), l2=f2bf(a2-bf2f(h2)), l3=f2bf(a3-bf2f(h3));
  ((u64t*)hi)[i] = (u64t)h0 | ((u64t)h1<<16) | ((u64t)h2<<32) | ((u64t)h3<<48);
  ((u64t*)lo)[i] = (u64t)l0 | ((u64t)l1<<16) | ((u64t)l2<<32) | ((u64t)l3<<48);
}

__global__ __launch_bounds__(256) void cvt_kernel(const float* __restrict__ src,
    u16t* __restrict__ dst, int n4){
  int i = blockIdx.x * 256 + threadIdx.x;
  if (i >= n4) return;
  float4 v = ((const float4*)src)[i];
  u16t h0=f2bf(v.x), h1=f2bf(v.y), h2=f2bf(v.z), h3=f2bf(v.w);
  ((u64t*)dst)[i] = (u64t)h0 | ((u64t)h1<<16) | ((u64t)h2<<32) | ((u64t)h3<<48);
}

// ---------------- QKV GEMM: C[8192,3072] = (xh+xl)(Wh+Wl)^T + b, split 3-pass ----------------
__global__ __launch_bounds__(256) void qkv_gemm_kernel(
    const u16t* __restrict__ Ah, const u16t* __restrict__ Al,
    const u16t* __restrict__ Bh, const u16t* __restrict__ Bl,
    const float* __restrict__ bias,
    float* __restrict__ qout, u16t* __restrict__ khi, u16t* __restrict__ klo,
    u16t* __restrict__ vt)
{
  __shared__ u16t lds[4*4096];
  const int tid = threadIdx.x;
  const int l = tid & 63, w = tid >> 6;
  const int wr = w >> 1, wc = w & 1;
  const int mt = blockIdx.y, nt = blockIdx.x;
  f32x4 acc[4][4] = {};
  for (int ks = 0; ks < 32; ++ks){
    __syncthreads();
    #pragma unroll
    for (int p = 0; p < 4; ++p){
      const u16t* src = (p==0) ? Ah : (p==1) ? Al : (p==2) ? Bh : Bl;
      int rb = ((p < 2) ? mt : nt) * 128;
      #pragma unroll
      for (int ii = 0; ii < 2; ++ii){
        int c = tid + ii*256;
        int row = c >> 2, kc = c & 3;
        s16x8 v = *(const s16x8*)(src + (size_t)(rb + row)*1024 + ks*32 + kc*8);
        *(s16x8*)((char*)lds + p*8192 + ((row*64 + kc*16) ^ SWZ(row))) = v;
      }
    }
    __syncthreads();
    s16x8 afh[4], afl[4], bfh[4], bfl[4];
    const int kb = (l >> 4) * 16;
    #pragma unroll
    for (int i = 0; i < 4; ++i){
      int row = wr*64 + i*16 + (l & 15);
      int off = (row*64 + kb) ^ SWZ(row);
      afh[i] = *(const s16x8*)((char*)lds + off);
      afl[i] = *(const s16x8*)((char*)lds + 8192 + off);
    }
    #pragma unroll
    for (int j = 0; j < 4; ++j){
      int row = wc*64 + j*16 + (l & 15);
      int off = (row*64 + kb) ^ SWZ(row);
      bfh[j] = *(const s16x8*)((char*)lds + 16384 + off);
      bfl[j] = *(const s16x8*)((char*)lds + 24576 + off);
    }
    #pragma unroll
    for (int i = 0; i < 4; ++i)
      #pragma unroll
      for (int j = 0; j < 4; ++j){
        acc[i][j] = mfma16(afh[i], bfh[j], acc[i][j]);
        acc[i][j] = mfma16(afh[i], bfl[j], acc[i][j]);
        acc[i][j] = mfma16(afl[i], bfh[j], acc[i][j]);
      }
  }
  #pragma unroll
  for (int j = 0; j < 4; ++j){
    int col = nt*128 + wc*64 + j*16 + (l & 15);
    float bv = bias[col];
    #pragma unroll
    for (int i = 0; i < 4; ++i){
      int tok0 = mt*128 + wr*64 + i*16 + (l >> 4)*4;
      int b = tok0 >> 11;
      int s0 = tok0 & 2047;
      if (col < 1024){
        int h = col >> 6, d = col & 63;
        float* dst = qout + ((size_t)(b*NH + h)*NS + s0)*64 + d;
        #pragma unroll
        for (int r = 0; r < 4; ++r) dst[(size_t)r*64] = acc[i][j][r] + bv;
      } else if (col < 2048){
        int ch = col - 1024; int h = ch >> 6, d = ch & 63;
        size_t idx = ((size_t)(b*NH + h)*NS + s0)*64 + d;
        #pragma unroll
        for (int r = 0; r < 4; ++r){
          float v0 = acc[i][j][r] + bv;
          u16t hh = f2bf(v0);
          khi[idx + (size_t)r*64] = hh;
          klo[idx + (size_t)r*64] = f2bf(v0 - bf2f(hh));
        }
      } else {
        int ch = col - 2048; int h = ch >> 6, d = ch & 63;
        u32t p0 = (u32t)f2bf(acc[i][j][0] + bv) | ((u32t)f2bf(acc[i][j][1] + bv) << 16);
        u32t p1 = (u32t)f2bf(acc[i][j][2] + bv) | ((u32t)f2bf(acc[i][j][3] + bv) << 16);
        u64t pk = (u64t)p0 | ((u64t)p1 << 32);
        *(u64t*)(vt + ((size_t)(b*NH + h)*64 + d)*NS + s0) = pk;
      }
    }
  }
}

// ---------------- out GEMM ----------------
__global__ __launch_bounds__(256) void out_gemm_kernel(
    const u16t* __restrict__ A, const u16t* __restrict__ Bt,
    const float* __restrict__ bias, float* __restrict__ Y)
{
  __shared__ u16t lds[2*4096];
  const int tid = threadIdx.x;
  const int l = tid & 63, w = tid >> 6;
  const int wr = w >> 1, wc = w & 1;
  const int mt = blockIdx.y, nt = blockIdx.x;
  f32x4 acc[4][4] = {};
  for (int ks = 0; ks < 32; ++ks){
    __syncthreads();
    #pragma unroll
    for (int p = 0; p < 2; ++p){
      const u16t* src = p ? Bt : A;
      int rb = (p ? nt : mt) * 128;
      #pragma unroll
      for (int ii = 0; ii < 2; ++ii){
        int c = tid + ii*256;
        int row = c >> 2, kc = c & 3;
        s16x8 v = *(const s16x8*)(src + (size_t)(rb + row)*1024 + ks*32 + kc*8);
        *(s16x8*)((char*)lds + p*8192 + ((row*64 + kc*16) ^ SWZ(row))) = v;
      }
    }
    __syncthreads();
    s16x8 af[4], bf[4];
    const int kb = (l >> 4) * 16;
    #pragma unroll
    for (int i = 0; i < 4; ++i){
      int row = wr*64 + i*16 + (l & 15);
      af[i] = *(const s16x8*)((char*)lds + ((row*64 + kb) ^ SWZ(row)));
    }
    #pragma unroll
    for (int j = 0; j < 4; ++j){
      int row = wc*64 + j*16 + (l & 15);
      bf[j] = *(const s16x8*)((char*)lds + 8192 + ((row*64 + kb) ^ SWZ(row)));
    }
    #pragma unroll
    for (int i = 0; i < 4; ++i)
      #pragma unroll
      for (int j = 0; j < 4; ++j)
        acc[i][j] = mfma16(af[i], bf[j], acc[i][j]);
  }
  #pragma unroll
  for (int j = 0; j < 4; ++j){
    int col = nt*128 + wc*64 + j*16 + (l & 15);
    float bv = bias[col];
    #pragma unroll
    for (int i = 0; i < 4; ++i){
      int tok0 = mt*128 + wr*64 + i*16 + (l >> 4)*4;
      float* dst = Y + (size_t)tok0*1024 + col;
      #pragma unroll
      for (int r = 0; r < 4; ++r) dst[(size_t)r*1024] = acc[i][j][r] + bv;
    }
  }
}

// ---------------- fused sparse attention: 1 WG = (bh, 16 q-rows), 2 blocks/CU ----------------
// Phase 1: u16 exp-keys via mfma(K,Q), K hi/lo frags direct from global (prefetched) -> LDS
// Phase 2: per-row exact 204th-largest key via wave binary search (keys in regs),
//          exp2 weights prescaled 1/Z, in-place in LDS
// Phase 3: PV via mfma(V^T, W), V frags direct from global (prefetched), W from LDS
__global__ __launch_bounds__(256) void attn_fused_kernel(
    const float* __restrict__ qbuf, const u16t* __restrict__ khi,
    const u16t* __restrict__ klo, const u16t* __restrict__ vtg,
    u16t* __restrict__ aout)
{
  extern __shared__ char smem[];   // 65536: [16][2048] u16 keys -> bf16 weights, swizzled
  const int tid = threadIdx.x;
  const int l = tid & 63, w = tid >> 6;
  int lid = ((blockIdx.x & 7) << 10) | (blockIdx.x >> 3); // XCD-chunked swizzle (8192%8==0)
  const int bh = lid >> 7, qt = lid & 127;
  const int qrow = l & 15;
  const size_t kbase = (size_t)bh*NS*64 + (l >> 4)*8;

  // Phase 0: Q fragments (B operand): row = qrow, d-slice = c*32 + (l>>4)*8
  s16x8 qh[2], ql[2];
  {
    const float* qp = qbuf + ((size_t)bh*NS + qt*16 + qrow)*64 + (l >> 4)*8;
    #pragma unroll
    for (int c = 0; c < 2; ++c){
      float4 va = *(const float4*)(qp + c*32);
      float4 vb = *(const float4*)(qp + c*32 + 4);
      float vv[8] = {va.x,va.y,va.z,va.w,vb.x,vb.y,vb.z,vb.w};
      #pragma unroll
      for (int e = 0; e < 8; ++e){
        u16t hh = f2bf(vv[e]);
        qh[c][e] = (short)hh;
        ql[c][e] = (short)f2bf(vv[e] - bf2f(hh));
      }
    }
  }

  // Phase 1: keys. Wave w handles toks g*64 + w*16 .. +15 for g = 0..31.
  s16x8 nh0, nh1, nl0, nl1;
  {
    size_t a = kbase + (size_t)(w*16 + qrow)*64;
    nh0 = *(const s16x8*)(khi + a);
    nh1 = *(const s16x8*)(khi + a + 32);
    nl0 = *(const s16x8*)(klo + a);
    nl1 = *(const s16x8*)(klo + a + 32);
  }
  for (int g = 0; g < 32; ++g){
    s16x8 h0 = nh0, h1 = nh1, g0 = nl0, g1 = nl1;
    if (g + 1 < 32){
      size_t a = kbase + (size_t)((g+1)*64 + w*16 + qrow)*64;
      nh0 = *(const s16x8*)(khi + a);
      nh1 = *(const s16x8*)(khi + a + 32);
      nl0 = *(const s16x8*)(klo + a);
      nl1 = *(const s16x8*)(klo + a + 32);
    }
    f32x4 acc = {};
    acc = mfma16(h0, qh[0], acc);
    acc = mfma16(h1, qh[1], acc);
    acc = mfma16(h0, ql[0], acc);
    acc = mfma16(h1, ql[1], acc);
    acc = mfma16(g0, qh[0], acc);
    acc = mfma16(g1, qh[1], acc);
    // lane holds C[tok][qrow]: 4 consecutive toks (g*64 + w*16 + (l>>4)*4 + r) for one qrow
    int t0 = g*64 + w*16 + (l >> 4)*4;
    u32t k0 = mkkey(acc[0]), k1 = mkkey(acc[1]);
    u32t k2 = mkkey(acc[2]), k3 = mkkey(acc[3]);
    u64t pk = (u64t)(k0 | (k1 << 16)) | ((u64t)(k2 | (k3 << 16)) << 32);
    *(u64t*)(smem + ((qrow*4096 + t0*2) ^ SWZ(qrow))) = pk;
  }
  __syncthreads();

  // Phase 2: rows w*4..w*4+3; exact threshold on keys + weights (in-place)
  for (int rr = 0; rr < 4; ++rr){
    int row = w*4 + rr;
    int rb = row*4096, rs = SWZ(row);
    u32t ku[16], kl[16];
    #pragma unroll
    for (int i = 0; i < 4; ++i){
      u32x4 v = *(const u32x4*)(smem + ((rb + i*1024 + l*16) ^ rs));
      #pragma unroll
      for (int j = 0; j < 4; ++j){ ku[i*4+j] = v[j]; kl[i*4+j] = v[j] << 16; }
    }
    // row max key
    u32t mh = 0, ml = 0;
    #pragma unroll
    for (int i = 0; i < 16; ++i){
      mh = mh > ku[i] ? mh : ku[i];
      ml = ml > kl[i] ? ml : kl[i];
    }
    u32t km = mh >> 16, m2 = ml >> 16;
    km = km > m2 ? km : m2;
    #pragma unroll
    for (int o = 32; o; o >>= 1){
      u32t t = (u32t)__shfl_xor((int)km, o);
      km = km > t ? km : t;
    }

    #define CNTLT(mid, out) {                                   \
      u32t mm = (mid) << 16;                                    \
      u32t c0=0,c1=0,c2=0,c3=0;                                 \
      _Pragma("unroll")                                         \
      for (int i = 0; i < 16; i += 4){                          \
        c0 += (ku[i  ] < mm) + (kl[i  ] < mm);                  \
        c1 += (ku[i+1] < mm) + (kl[i+1] < mm);                  \
        c2 += (ku[i+2] < mm) + (kl[i+2] < mm);                  \
        c3 += (ku[i+3] < mm) + (kl[i+3] < mm);                  \
      }                                                         \
      u32t cc = (c0+c1)+(c2+c3);                                \
      _Pragma("unroll")                                         \
      for (int o = 32; o; o >>= 1) cc += (u32t)__shfl_xor((int)cc, o); \
      out = cc;                                                 \
    }

    u32t lo, hi, cseed;
    CNTLT(32768u, cseed);
    if (2048u - cseed >= (u32t)TOPK){ lo = 32768u; hi = km; }
    else                            { lo = 0u;     hi = 32767u; }
    while (lo < hi){
      u32t mid = (lo + hi + 1u) >> 1;
      u32t c; CNTLT(mid, c);
      if (2048u - c >= (u32t)TOPK) lo = mid; else hi = mid - 1u;
    }
    const u32t kbt = lo;

    const u32t kmxe = km < 32768u ? 32768u : km;
    const float dsh = -(float)kmxe * 0.0009765625f;
    const float em = exp2f(fmaf(32768.0f, 0.0009765625f, dsh));
    float wv[32];
    float zs = 0.0f;
    #pragma unroll
    for (int i = 0; i < 16; ++i){
      u32t x0 = ku[i] & 0xFFFFu, x1 = ku[i] >> 16;
      float e0 = exp2f(fmaf((float)x0, 0.0009765625f, dsh));
      float e1 = exp2f(fmaf((float)x1, 0.0009765625f, dsh));
      wv[2*i]   = (x0 >= kbt) ? e0 : em;
      wv[2*i+1] = (x1 >= kbt) ? e1 : em;
      zs += wv[2*i] + wv[2*i+1];
    }
    #pragma unroll
    for (int o = 32; o; o >>= 1) zs += __shfl_xor(zs, o);
    const float zinv = 1.0f / (zs + 1e-9f);
    #pragma unroll
    for (int i = 0; i < 4; ++i){
      u32x4 o;
      #pragma unroll
      for (int j = 0; j < 4; ++j){
        int e = 2*(i*4+j);
        o[j] = pk_bf16(wv[e]*zinv, wv[e+1]*zinv);
      }
      *(u32x4*)(smem + ((rb + i*1024 + l*16) ^ rs)) = o;
    }
    #undef CNTLT
  }
  __syncthreads();

  // Phase 3: PV via mfma(V^T, W): C[d][qrow]. Wave w owns d-block w*16..+15.
  f32x4 pacc = {};
  const u16t* vp = vtg + ((size_t)bh*64 + w*16 + qrow)*NS + (l >> 4)*8;
  s16x8 nv0 = *(const s16x8*)(vp);
  s16x8 nv1 = *(const s16x8*)(vp + 32);
  for (int kt = 0; kt < 32; ++kt){
    s16x8 v0 = nv0, v1 = nv1;
    if (kt + 1 < 32){
      nv0 = *(const s16x8*)(vp + (kt+1)*64);
      nv1 = *(const s16x8*)(vp + (kt+1)*64 + 32);
    }
    int tb = (kt*64 + (l >> 4)*8)*2;
    s16x8 w0 = *(const s16x8*)(smem + ((qrow*4096 + tb) ^ SWZ(qrow)));
    s16x8 w1 = *(const s16x8*)(smem + ((qrow*4096 + tb + 64) ^ SWZ(qrow)));
    pacc = mfma16(v0, w0, pacc);
    pacc = mfma16(v1, w1, pacc);
  }
  // epilogue: lane holds C[d][qrow], d = w*16 + (l>>4)*4 + r; weights carry 1/Z
  {
    int tok = qt*16 + qrow;
    int b = bh >> 4, h = bh & 15;
    int d0 = w*16 + (l >> 4)*4;
    u32t p0 = pk_bf16(pacc[0], pacc[1]);
    u32t p1 = pk_bf16(pacc[2], pacc[3]);
    *(u64t*)(aout + ((size_t)(b*NS + tok))*1024 + h*64 + d0) = (u64t)p0 | ((u64t)p1 << 32);
  }
}

// ---------------- workspace layout (132.1 MB, proven available) ----------------
#define O_XHI  ((size_t)0)
#define O_XLO  (O_XHI + (size_t)NTOK*ND*2)
#define O_WQH  (O_XLO + (size_t)NTOK*ND*2)
#define O_WQL  (O_WQH + (size_t)3072*1024*2)
#define O_WOB  (O_WQL + (size_t)3072*1024*2)
#define O_Q    (O_WOB + (size_t)1024*1024*2)
#define O_KHI  (O_Q   + (size_t)NBH*NS*64*4)
#define O_KLO  (O_KHI + (size_t)NBH*NS*64*2)
#define O_VT   (O_KLO + (size_t)NBH*NS*64*2)
#define O_AOUT O_XHI   /* alias: x_hi dead after QKV GEMM */
#define WS_NEED (O_VT + (size_t)NBH*NS*64*2)

extern "C" void kernel_launch(void* const* d_in, const int* in_sizes, int n_in,
                              void* d_out, int out_size, void* d_ws, size_t ws_size,
                              hipStream_t stream)
{
  (void)in_sizes; (void)n_in; (void)out_size;
  const float* x    = (const float*)d_in[0];
  const float* Wqkv = (const float*)d_in[1];
  const float* bqkv = (const float*)d_in[2];
  const float* Wo   = (const float*)d_in[3];
  const float* bo   = (const float*)d_in[4];
  float* Y = (float*)d_out;
  char* ws = (char*)d_ws;
  if (ws_size < WS_NEED) return;

  u16t* xhi  = (u16t*)(ws + O_XHI);
  u16t* xlo  = (u16t*)(ws + O_XLO);
  u16t* wqh  = (u16t*)(ws + O_WQH);
  u16t* wql  = (u16t*)(ws + O_WQL);
  u16t* wob  = (u16t*)(ws + O_WOB);
  float* qbuf = (float*)(ws + O_Q);
  u16t* khi  = (u16t*)(ws + O_KHI);
  u16t* klo  = (u16t*)(ws + O_KLO);
  u16t* vt   = (u16t*)(ws + O_VT);
  u16t* aout = (u16t*)(ws + O_AOUT);

  hipFuncSetAttribute((const void*)attn_fused_kernel,
                      hipFuncAttributeMaxDynamicSharedMemorySize, 65536);

  split_pair_kernel<<<(NTOK*ND/4)/256, 256, 0, stream>>>(x, xhi, xlo, NTOK*ND/4);
  split_pair_kernel<<<(3072*1024/4)/256, 256, 0, stream>>>(Wqkv, wqh, wql, 3072*1024/4);
  cvt_kernel<<<(1024*1024/4)/256, 256, 0, stream>>>(Wo, wob, 1024*1024/4);
  qkv_gemm_kernel<<<dim3(24, 64), 256, 0, stream>>>(xhi, xlo, wqh, wql, bqkv,
                                                    qbuf, khi, klo, vt);
  attn_fused_kernel<<<8192, 256, 65536, stream>>>(qbuf, khi, klo, vt, aout);
  out_gemm_kernel<<<dim3(8, 64), 256, 0, stream>>>(aout, wob, bo, Y);
}